// Round 1
// baseline (3730.964 us; speedup 1.0000x reference)
//
#include <hip/hip_runtime.h>
#include <hip/hip_cooperative_groups.h>

namespace cg = cooperative_groups;

typedef unsigned short u16;
typedef short s16x8 __attribute__((ext_vector_type(8)));
typedef float f32x4 __attribute__((ext_vector_type(4)));

#define LAYERS   64
#define M_NODES  2048
#define DIM      128
#define FD       512
#define CHUNK    16
#define NBLK     128     // M_NODES / CHUNK
#define TPB      512     // 8 waves; wave wv owns hidden dims [wv*16, wv*16+16)
#define XPAD     136     // 128 + 8 pad u16 (16B-aligned rows)

__device__ __forceinline__ u16 f2bf(float f) {
    union { float f; unsigned int i; } v; v.f = f;
    unsigned int r = (v.i + 0x7FFFu + ((v.i >> 16) & 1u)) >> 16;
    return (u16)r;
}
__device__ __forceinline__ float sigm(float x) {
    return __builtin_amdgcn_rcpf(1.0f + __builtin_exp2f(-1.44269504f * x));
}
__device__ __forceinline__ float tanh_f(float x) {
    float ax = __builtin_fabsf(x);
    float t  = __builtin_exp2f(-2.88539008f * ax);   // exp(-2|x|)
    float r  = (1.0f - t) * __builtin_amdgcn_rcpf(1.0f + t);
    return __builtin_copysignf(r, x);
}

// ---------------- layer 0: emb[m] = basic_table[basic_names[m]]  (fp32 copy) ----------------
__global__ void l0_kernel(const int* __restrict__ names, const float* __restrict__ table,
                          float* __restrict__ emb) {
    int v = blockIdx.x * blockDim.x + threadIdx.x;      // 2048 rows * 32 float4
    if (v >= M_NODES * (DIM / 4)) return;
    int row = v >> 5, c = v & 31;
    const float4* src = (const float4*)(table + (size_t)names[row] * DIM);
    ((float4*)(emb + (size_t)row * DIM))[c] = src[c];
}

// ------------- repack W_m,U_m,W_s,U_s (fp32) into bf16 MFMA B-fragments in d_ws -------------
// packed[(((mat*4 + kc)*32 + ntile)*64 + lane)*8 + j] = bf16(B[kc*32 + (lane>>4)*8 + j][ntile*16 + (lane&15)])
__global__ void repack_kernel(const float* __restrict__ Wm, const float* __restrict__ Um,
                              const float* __restrict__ Ws, const float* __restrict__ Us,
                              u16* __restrict__ packed) {
    int t = blockIdx.x * blockDim.x + threadIdx.x;      // 4*4*32*64 = 32768 threads
    if (t >= 4 * 4 * 32 * 64) return;
    int lane = t & 63, ntg = (t >> 6) & 31, kc = (t >> 11) & 3, mat = t >> 13;
    const float* B = (mat == 0) ? Wm : (mat == 1) ? Um : (mat == 2) ? Ws : Us;
    int q = lane >> 4, nl = lane & 15;
    int kb = kc * 32 + q * 8;
    int n  = ntg * 16 + nl;
    u16* dst = packed + ((((size_t)mat * 4 + kc) * 32 + ntg) * 64 + lane) * 8;
    #pragma unroll
    for (int j = 0; j < 8; j++) dst[j] = f2bf(B[(size_t)(kb + j) * FD + n]);
}

// ======================= persistent fused kernel: all 63 layers, one launch =======================
// Per layer: gather -> precompute Zx = x@W for all non-recurrent inputs -> recurrent steps do only
// h@U (4-deep MFMA chain) + gates. LSTM_m t=0 (x=empty, h=0) is layer-invariant: c1/h1/uh1 hoisted
// out of the loop, so phase m t=1 needs no barrier and no LDS read. grid.sync() between layers.
template <bool PACKED>
__global__ __launch_bounds__(TPB, 2) void fused_kernel(
    float* __restrict__ emb, const int* __restrict__ prop_ids, const int* __restrict__ super_ids,
    const float* __restrict__ Wm, const float* __restrict__ Um, const float* __restrict__ bm,
    const float* __restrict__ Ws, const float* __restrict__ Us, const float* __restrict__ bs,
    const float* __restrict__ empty, const u16* __restrict__ packed) {

    cg::grid_group grid = cg::this_grid();

    // slots 0..3: prop embeddings (slot 0 reused for h_m); slots 4..5: super embeddings
    __shared__ __align__(16) u16  xs[6][CHUNK][XPAD];   // bf16 A-operand tiles
    __shared__ __align__(16) u16  hbuf[2][CHUNK][XPAD]; // bf16 h state, double-buffered
    __shared__ float h1_s[DIM];

    const int tid  = threadIdx.x;
    const int b    = blockIdx.x;
    const int g0   = b * CHUNK;
    const int wv   = tid >> 6;          // 0..7
    const int lane = tid & 63;
    const int q    = lane >> 4, nl = lane & 15;
    const int d    = wv * 16 + nl;      // this lane's hidden dim

    auto ldB = [&](const float* B, int mat, int kc, int g) -> s16x8 {
        if (PACKED) {
            return *(const s16x8*)(packed + ((((size_t)mat * 4 + kc) * 32 + (g * 8 + wv)) * 64 + lane) * 8);
        } else {
            int kb = kc * 32 + q * 8;
            int n  = g * 128 + d;
            s16x8 f;
            #pragma unroll
            for (int j = 0; j < 8; j++) f[j] = (short)f2bf(B[(size_t)(kb + j) * FD + n]);
            return f;
        }
    };
    auto load_afrag = [&](const u16* X /* [CHUNK][XPAD] base */, int kc) -> s16x8 {
        return *(const s16x8*)(X + (size_t)nl * XPAD + kc * 32 + q * 8);
    };

    float bzm[4], bzs[4];
    #pragma unroll
    for (int g = 0; g < 4; g++) { bzm[g] = bm[g * 128 + d]; bzs[g] = bs[g * 128 + d]; }

    // ---- layer-invariant LSTM_m t=0: x = empty, h = c = 0 (f32, once per kernel) ----
    float c1, h1;
    {
        float z0 = bzm[0], z1 = bzm[1], z2 = bzm[2], z3 = bzm[3];
        for (int k = 0; k < DIM; k++) {
            float e = empty[k];
            const float* Wr = Wm + (size_t)k * FD + d;
            z0 += e * Wr[0]; z1 += e * Wr[128]; z2 += e * Wr[256]; z3 += e * Wr[384];
        }
        (void)z1;                                   // f-gate irrelevant at c_prev = 0
        c1 = sigm(z0) * tanh_f(z2);                 // gate order i,f,g,o
        h1 = sigm(z3) * tanh_f(c1);
        if (q == 0) h1_s[d] = h1;                   // q==0 lanes cover all 128 dims
    }
    __syncthreads();

    // uh1[g] = (bf16(h1) @ U_m)[g*128+d]  — same bf16 product the recurrent path would compute
    float uh1[4];
    {
        s16x8 ha[4];
        #pragma unroll
        for (int kc = 0; kc < 4; kc++)
            #pragma unroll
            for (int j = 0; j < 8; j++) ha[kc][j] = (short)f2bf(h1_s[kc * 32 + q * 8 + j]);
        f32x4 acc[4];
        #pragma unroll
        for (int g = 0; g < 4; g++) acc[g] = (f32x4){0.f, 0.f, 0.f, 0.f};
        #pragma unroll
        for (int kc = 0; kc < 4; kc++) {
            #pragma unroll
            for (int g = 0; g < 4; g++) {
                s16x8 u = ldB(Um, 1, kc, g);
                acc[g] = __builtin_amdgcn_mfma_f32_16x16x32_bf16(ha[kc], u, acc[g], 0, 0, 0);
            }
        }
        #pragma unroll
        for (int g = 0; g < 4; g++) uh1[g] = acc[g][0];  // all rows identical
    }

    // gates + store; mode 0: hbuf[parity], 1: xs[0] (h_m), 2: emb (fp32 out)
    auto gates = [&](f32x4* acc, const float* bz, float* cc, int mode, int parity, int l) {
        #pragma unroll
        for (int r2 = 0; r2 < 4; r2++) {
            int m = q * 4 + r2;
            float zi = acc[0][r2] + bz[0];
            float zf = acc[1][r2] + bz[1];
            float zg = acc[2][r2] + bz[2];
            float zo = acc[3][r2] + bz[3];
            float c  = sigm(zf) * cc[r2] + sigm(zi) * tanh_f(zg);
            cc[r2] = c;
            float h  = sigm(zo) * tanh_f(c);
            if (mode == 0)      hbuf[parity][m][d] = f2bf(h);
            else if (mode == 1) xs[0][m][d] = f2bf(h);
            else emb[((size_t)l * M_NODES + g0 + m) * DIM + d] = h;
        }
    };

    for (int l = 1; l < LAYERS; l++) {
        // gather indices are pure inputs — prefetch before the grid sync
        size_t gidx = 0; int quarter = 0, slot = 0, node = 0;
        if (tid < 384) {
            quarter = tid & 3;
            int r = tid >> 2;
            slot = r >> 4;
            node = r & 15;
            if (slot < 4) gidx = (size_t)prop_ids [((size_t)l * M_NODES + g0 + node) * 4 + slot];
            else          gidx = (size_t)super_ids[((size_t)l * M_NODES + g0 + node) * 2 + (slot - 4)];
        }
        if (l > 1) { __threadfence(); grid.sync(); }   // layer l-1 emb writes visible grid-wide

        // ---- gather: 96 fp32 rows -> bf16 LDS tiles ----
        if (tid < 384) {
            const float4* src = (const float4*)(emb + gidx * DIM);
            u16* dst = &xs[slot][node][0];
            int e0 = quarter * 32;
            #pragma unroll
            for (int j = 0; j < 8; j++) {
                float4 v = src[(e0 >> 2) + j];
                int o = e0 + j * 4;
                dst[o] = f2bf(v.x); dst[o + 1] = f2bf(v.y);
                dst[o + 2] = f2bf(v.z); dst[o + 3] = f2bf(v.w);
            }
        }
        __syncthreads();

        // ---- Zx precompute: x@W for prop0..3 (the only x@W the recurrence can't see yet is h_m@W_s) ----
        f32x4 zxm[4][4];
        {
            s16x8 wf[4][4];
            #pragma unroll
            for (int kc = 0; kc < 4; kc++)
                #pragma unroll
                for (int g = 0; g < 4; g++) wf[kc][g] = ldB(Wm, 0, kc, g);
            #pragma unroll
            for (int s = 0; s < 4; s++) {
                #pragma unroll
                for (int g = 0; g < 4; g++) zxm[s][g] = (f32x4){0.f, 0.f, 0.f, 0.f};
                #pragma unroll
                for (int kc = 0; kc < 4; kc++) {
                    s16x8 a = load_afrag(&xs[s][0][0], kc);
                    #pragma unroll
                    for (int g = 0; g < 4; g++)
                        zxm[s][g] = __builtin_amdgcn_mfma_f32_16x16x32_bf16(a, wf[kc][g], zxm[s][g], 0, 0, 0);
                }
            }
        }

        // ---- recurrent LSTM_m: t=1..4 (t=0 hoisted) ----
        {
            s16x8 uf[4][4];
            #pragma unroll
            for (int kc = 0; kc < 4; kc++)
                #pragma unroll
                for (int g = 0; g < 4; g++) uf[kc][g] = ldB(Um, 1, kc, g);
            float cc[4] = {c1, c1, c1, c1};
            {   // t=1: z = x1@W + h1@U + b, all in registers — no barrier, no LDS read
                f32x4 acc[4];
                #pragma unroll
                for (int g = 0; g < 4; g++) acc[g] = zxm[0][g] + uh1[g];
                gates(acc, bzm, cc, 0, 1, l);          // write hbuf[1]
            }
            #pragma unroll
            for (int t = 2; t <= 4; t++) {             // read hbuf[(t-1)&1], write hbuf[t&1]
                __syncthreads();
                const u16* hb = &hbuf[(t - 1) & 1][0][0];
                f32x4 acc[4];
                #pragma unroll
                for (int g = 0; g < 4; g++) acc[g] = zxm[t - 1][g];
                #pragma unroll
                for (int kc = 0; kc < 4; kc++) {
                    s16x8 a = load_afrag(hb, kc);
                    #pragma unroll
                    for (int g = 0; g < 4; g++)
                        acc[g] = __builtin_amdgcn_mfma_f32_16x16x32_bf16(a, uf[kc][g], acc[g], 0, 0, 0);
                }
                if (t < 4) gates(acc, bzm, cc, 0, t & 1, l);
                else       gates(acc, bzm, cc, 1, 0, l);   // h_m -> xs[0]
            }
        }

        // ---- recurrent LSTM_s: seq = [sup0, sup1, h_m] ----
        {
            s16x8 uf[4][4], wf[4][4];
            #pragma unroll
            for (int kc = 0; kc < 4; kc++)
                #pragma unroll
                for (int g = 0; g < 4; g++) {
                    uf[kc][g] = ldB(Us, 3, kc, g);
                    wf[kc][g] = ldB(Ws, 2, kc, g);     // needed at t=1 (zxs1) and t=2 (h_m@W)
                }
            // zxs: sup0 (used immediately at t=0) and sup1 (held for t=1)
            f32x4 acc0[4], zxs1[4];
            #pragma unroll
            for (int g = 0; g < 4; g++) { acc0[g] = (f32x4){0.f,0.f,0.f,0.f}; zxs1[g] = (f32x4){0.f,0.f,0.f,0.f}; }
            #pragma unroll
            for (int kc = 0; kc < 4; kc++) {
                s16x8 a4 = load_afrag(&xs[4][0][0], kc);
                s16x8 a5 = load_afrag(&xs[5][0][0], kc);
                #pragma unroll
                for (int g = 0; g < 4; g++) {
                    acc0[g] = __builtin_amdgcn_mfma_f32_16x16x32_bf16(a4, wf[kc][g], acc0[g], 0, 0, 0);
                    zxs1[g] = __builtin_amdgcn_mfma_f32_16x16x32_bf16(a5, wf[kc][g], zxs1[g], 0, 0, 0);
                }
            }
            float cc[4] = {0.f, 0.f, 0.f, 0.f};
            gates(acc0, bzs, cc, 0, 0, l);             // t=0: h=0, write hbuf[0] (safe: after m-t4's barrier)
            {   // t=1: x=sup1
                __syncthreads();
                const u16* hb = &hbuf[0][0][0];
                f32x4 acc[4];
                #pragma unroll
                for (int g = 0; g < 4; g++) acc[g] = zxs1[g];
                #pragma unroll
                for (int kc = 0; kc < 4; kc++) {
                    s16x8 a = load_afrag(hb, kc);
                    #pragma unroll
                    for (int g = 0; g < 4; g++)
                        acc[g] = __builtin_amdgcn_mfma_f32_16x16x32_bf16(a, uf[kc][g], acc[g], 0, 0, 0);
                }
                gates(acc, bzs, cc, 0, 1, l);          // write hbuf[1]
            }
            {   // t=2: x=h_m (xs[0]) — both x@W and h@U here
                __syncthreads();
                const u16* hb = &hbuf[1][0][0];
                f32x4 acc[4];
                #pragma unroll
                for (int g = 0; g < 4; g++) acc[g] = (f32x4){0.f, 0.f, 0.f, 0.f};
                #pragma unroll
                for (int kc = 0; kc < 4; kc++) {
                    s16x8 a  = load_afrag(&xs[0][0][0], kc);
                    s16x8 ah = load_afrag(hb, kc);
                    #pragma unroll
                    for (int g = 0; g < 4; g++) {
                        acc[g] = __builtin_amdgcn_mfma_f32_16x16x32_bf16(a,  wf[kc][g], acc[g], 0, 0, 0);
                        acc[g] = __builtin_amdgcn_mfma_f32_16x16x32_bf16(ah, uf[kc][g], acc[g], 0, 0, 0);
                    }
                }
                gates(acc, bzs, cc, 2, 0, l);          // fp32 layer output
            }
        }
    }
}

// ----------------------------- fallback: previous per-layer kernel (unchanged) -----------------------------
template <bool PACKED>
__global__ __launch_bounds__(TPB, 2) void layer_kernel(
    float* __restrict__ emb, const int* __restrict__ prop_ids, const int* __restrict__ super_ids,
    const float* __restrict__ Wm, const float* __restrict__ Um, const float* __restrict__ bm,
    const float* __restrict__ Ws, const float* __restrict__ Us, const float* __restrict__ bs,
    const float* __restrict__ empty, const u16* __restrict__ packed, int l) {

    __shared__ __align__(16) u16  xs[6][CHUNK][XPAD];
    __shared__ __align__(16) u16  hbuf[2][CHUNK][XPAD];
    __shared__ __align__(16) u16  empty_s[XPAD];

    const int tid  = threadIdx.x;
    const int b    = blockIdx.x;
    const int g0   = b * CHUNK;
    const size_t row0 = (size_t)l * M_NODES + g0;

    const int wv   = tid >> 6;
    const int lane = tid & 63;
    const int q    = lane >> 4, nl = lane & 15;
    const int d    = wv * 16 + nl;

    if (tid < 384) {
        int quarter = tid & 3;
        int r    = tid >> 2;
        int slot = r >> 4;
        int node = r & 15;
        size_t idx;
        if (slot < 4) idx = (size_t)prop_ids [((size_t)l * M_NODES + g0 + node) * 4 + slot];
        else          idx = (size_t)super_ids[((size_t)l * M_NODES + g0 + node) * 2 + (slot - 4)];
        const float4* src = (const float4*)(emb + idx * DIM);
        u16* dst = &xs[slot][node][0];
        int e0 = quarter * 32;
        #pragma unroll
        for (int j = 0; j < 8; j++) {
            float4 v = src[(e0 >> 2) + j];
            int o = e0 + j * 4;
            dst[o] = f2bf(v.x); dst[o + 1] = f2bf(v.y);
            dst[o + 2] = f2bf(v.z); dst[o + 3] = f2bf(v.w);
        }
    } else if (tid < 384 + 128) {
        int dd = tid - 384;
        empty_s[dd] = f2bf(empty[dd]);
    }
    __syncthreads();

    auto load_bfrag_packed = [&](int mat, int kc, int g) -> s16x8 {
        return *(const s16x8*)(packed + ((((size_t)mat * 4 + kc) * 32 + (g * 8 + wv)) * 64 + lane) * 8);
    };
    auto load_bfrag_direct = [&](const float* B, int kc, int g) -> s16x8 {
        int kb = kc * 32 + q * 8;
        int n  = g * 128 + d;
        s16x8 f;
        #pragma unroll
        for (int j = 0; j < 8; j++) f[j] = (short)f2bf(B[(size_t)(kb + j) * FD + n]);
        return f;
    };
    auto load_afrag = [&](const u16* X, int kc) -> s16x8 {
        return *(const s16x8*)(X + (size_t)nl * XPAD + kc * 32 + q * 8);
    };

    auto run_phase = [&](const float* Wg, const float* Ug, const float* bias,
                         int matW, int matU, int nsteps, const int* slots,
                         bool write_hm, bool write_out) {
        s16x8 wf[4][4], uf[4][4];
        #pragma unroll
        for (int kc = 0; kc < 4; kc++) {
            #pragma unroll
            for (int g = 0; g < 4; g++) {
                if (PACKED) { wf[kc][g] = load_bfrag_packed(matW, kc, g);
                              uf[kc][g] = load_bfrag_packed(matU, kc, g); }
                else        { wf[kc][g] = load_bfrag_direct(Wg, kc, g);
                              uf[kc][g] = load_bfrag_direct(Ug, kc, g); }
            }
        }
        float bz[4];
        #pragma unroll
        for (int g = 0; g < 4; g++) bz[g] = bias[g * 128 + d];
        float cc[4] = {0.f, 0.f, 0.f, 0.f};

        #pragma unroll 1
        for (int t = 0; t < nsteps; t++) {
            int s = slots[t];
            f32x4 acc[4];
            #pragma unroll
            for (int g = 0; g < 4; g++) acc[g] = (f32x4){0.f, 0.f, 0.f, 0.f};
            #pragma unroll
            for (int kc = 0; kc < 4; kc++) {
                s16x8 a = (s < 0) ? *(const s16x8*)(&empty_s[kc * 32 + q * 8])
                                  : load_afrag(&xs[s][0][0], kc);
                #pragma unroll
                for (int g = 0; g < 4; g++)
                    acc[g] = __builtin_amdgcn_mfma_f32_16x16x32_bf16(a, wf[kc][g], acc[g], 0, 0, 0);
            }
            if (t > 0) {
                __syncthreads();
                const u16* hb = &hbuf[(t - 1) & 1][0][0];
                #pragma unroll
                for (int kc = 0; kc < 4; kc++) {
                    s16x8 a = load_afrag(hb, kc);
                    #pragma unroll
                    for (int g = 0; g < 4; g++)
                        acc[g] = __builtin_amdgcn_mfma_f32_16x16x32_bf16(a, uf[kc][g], acc[g], 0, 0, 0);
                }
            }
            bool last = (t == nsteps - 1);
            #pragma unroll
            for (int r2 = 0; r2 < 4; r2++) {
                int m = q * 4 + r2;
                float zi = acc[0][r2] + bz[0];
                float zf = acc[1][r2] + bz[1];
                float zg = acc[2][r2] + bz[2];
                float zo = acc[3][r2] + bz[3];
                float c  = sigm(zf) * cc[r2] + sigm(zi) * tanh_f(zg);
                cc[r2] = c;
                float h  = sigm(zo) * tanh_f(c);
                if (!last)          hbuf[t & 1][m][d] = f2bf(h);
                else if (write_hm)  xs[0][m][d] = f2bf(h);
                else if (write_out) emb[(row0 + m) * DIM + d] = h;
            }
        }
    };

    {
        const int slots_m[5] = {-1, 0, 1, 2, 3};
        run_phase(Wm, Um, bm, 0, 1, 5, slots_m, true, false);
    }
    {
        const int slots_s[3] = {4, 5, 0};
        run_phase(Ws, Us, bs, 2, 3, 3, slots_s, false, true);
    }
}

extern "C" void kernel_launch(void* const* d_in, const int* in_sizes, int n_in,
                              void* d_out, int out_size, void* d_ws, size_t ws_size,
                              hipStream_t stream) {
    const int*   names = (const int*)d_in[0];
    const int*   pids  = (const int*)d_in[1];
    const int*   sids  = (const int*)d_in[2];
    const float* table = (const float*)d_in[3];
    const float* Wm    = (const float*)d_in[4];
    const float* Um    = (const float*)d_in[5];
    const float* bm    = (const float*)d_in[6];
    const float* Ws    = (const float*)d_in[7];
    const float* Us    = (const float*)d_in[8];
    const float* bs    = (const float*)d_in[9];
    const float* empt  = (const float*)d_in[10];
    float* emb  = (float*)d_out;
    u16* packed = (u16*)d_ws;

    l0_kernel<<<256, 256, 0, stream>>>(names, table, emb);

    const size_t packed_bytes = (size_t)4 * 4 * 32 * 64 * 8 * sizeof(u16);  // 512 KB
    const bool packed_ok = ws_size >= packed_bytes;
    if (packed_ok)
        repack_kernel<<<128, 256, 0, stream>>>(Wm, Um, Ws, Us, packed);

    // one persistent cooperative launch for layers 1..63
    void* args[] = {(void*)&emb, (void*)&pids, (void*)&sids, (void*)&Wm, (void*)&Um, (void*)&bm,
                    (void*)&Ws, (void*)&Us, (void*)&bs, (void*)&empt, (void*)&packed};
    void (*kptr)(float*, const int*, const int*, const float*, const float*, const float*,
                 const float*, const float*, const float*, const float*, const u16*) =
        packed_ok ? fused_kernel<true> : fused_kernel<false>;
    hipError_t err = hipLaunchCooperativeKernel((const void*)kptr, dim3(NBLK), dim3(TPB),
                                                args, 0, stream);
    if (err != hipSuccess) {
        // fallback: previous best per-layer path
        for (int l = 1; l < LAYERS; l++) {
            if (packed_ok)
                layer_kernel<true><<<NBLK, TPB, 0, stream>>>(emb, pids, sids, Wm, Um, bm,
                                                             Ws, Us, bs, empt, packed, l);
            else
                layer_kernel<false><<<NBLK, TPB, 0, stream>>>(emb, pids, sids, Wm, Um, bm,
                                                              Ws, Us, bs, empt, packed, l);
        }
    }
}

// Round 2
// 2210.480 us; speedup vs baseline: 1.6879x; 1.6879x over previous
//
#include <hip/hip_runtime.h>

typedef unsigned short u16;
typedef short s16x8 __attribute__((ext_vector_type(8)));
typedef float f32x4 __attribute__((ext_vector_type(4)));

#define LAYERS   64
#define M_NODES  2048
#define DIM      128
#define FD       512
#define CHUNK    16
#define NBLK     128     // M_NODES / CHUNK
#define TPB      512     // 8 waves; wave wv owns hidden dims [wv*16, wv*16+16)
#define XPAD     136     // 128 + 8 pad u16 (16B-aligned rows)

__device__ __forceinline__ u16 f2bf(float f) {
    union { float f; unsigned int i; } v; v.f = f;
    unsigned int r = (v.i + 0x7FFFu + ((v.i >> 16) & 1u)) >> 16;
    return (u16)r;
}
__device__ __forceinline__ float sigm(float x) {
    return __builtin_amdgcn_rcpf(1.0f + __builtin_exp2f(-1.44269504f * x));
}
__device__ __forceinline__ float tanh_f(float x) {
    float ax = __builtin_fabsf(x);
    float t  = __builtin_exp2f(-2.88539008f * ax);   // exp(-2|x|)
    float r  = (1.0f - t) * __builtin_amdgcn_rcpf(1.0f + t);
    return __builtin_copysignf(r, x);
}

// ---- cross-XCD coherent access: write-through / L2-bypass via sc0 sc1 (L3 = coherence point) ----
__device__ __forceinline__ void cload_f4(f32x4& v, const float* p) {
    asm volatile("global_load_dwordx4 %0, %1, off sc0 sc1" : "=&v"(v) : "v"(p));
}
__device__ __forceinline__ void cstore_f(float* p, float v) {
    asm volatile("global_store_dword %0, %1, off sc0 sc1" :: "v"(p), "v"(v) : "memory");
}

// ---------------- layer 0: emb[m] = basic_table[basic_names[m]]  (fp32 copy) ----------------
__global__ void l0_kernel(const int* __restrict__ names, const float* __restrict__ table,
                          float* __restrict__ emb) {
    int v = blockIdx.x * blockDim.x + threadIdx.x;      // 2048 rows * 32 float4
    if (v >= M_NODES * (DIM / 4)) return;
    int row = v >> 5, c = v & 31;
    const float4* src = (const float4*)(table + (size_t)names[row] * DIM);
    ((float4*)(emb + (size_t)row * DIM))[c] = src[c];
}

// ------------- repack W_m,U_m,W_s,U_s (fp32) into bf16 MFMA B-fragments in d_ws -------------
__global__ void repack_kernel(const float* __restrict__ Wm, const float* __restrict__ Um,
                              const float* __restrict__ Ws, const float* __restrict__ Us,
                              u16* __restrict__ packed, unsigned* __restrict__ bar) {
    int t = blockIdx.x * blockDim.x + threadIdx.x;      // 4*4*32*64 = 32768 threads
    if (t == 0) *bar = 0;                               // barrier counter reset (per graph run)
    if (t >= 4 * 4 * 32 * 64) return;
    int lane = t & 63, ntg = (t >> 6) & 31, kc = (t >> 11) & 3, mat = t >> 13;
    const float* B = (mat == 0) ? Wm : (mat == 1) ? Um : (mat == 2) ? Ws : Us;
    int q = lane >> 4, nl = lane & 15;
    int kb = kc * 32 + q * 8;
    int n  = ntg * 16 + nl;
    u16* dst = packed + ((((size_t)mat * 4 + kc) * 32 + ntg) * 64 + lane) * 8;
    #pragma unroll
    for (int j = 0; j < 8; j++) dst[j] = f2bf(B[(size_t)(kb + j) * FD + n]);
}

// ======================= persistent fused kernel: all 63 layers, one launch =======================
// Cross-layer coherence WITHOUT L2 flushes: emb stores are write-through (sc0 sc1 -> L3), gather
// loads bypass L1/L2 (sc0 sc1 <- L3), the grid barrier is RELAXED agent-scope atomics (no fence
// instructions => packed weights stay L2-hot for all 63 layers). Gather rows from layers < l-1
// are issued BEFORE the barrier so their L3 latency hides under the spin.
template <bool PACKED>
__global__ __launch_bounds__(TPB, 2) void fused_kernel(
    float* __restrict__ emb, const int* __restrict__ prop_ids, const int* __restrict__ super_ids,
    const float* __restrict__ Wm, const float* __restrict__ Um, const float* __restrict__ bm,
    const float* __restrict__ Ws, const float* __restrict__ Us, const float* __restrict__ bs,
    const float* __restrict__ empty, const u16* __restrict__ packed, unsigned* __restrict__ bar) {

    // slots 0..3: prop embeddings (slot 0 reused for h_m); slots 4..5: super embeddings
    __shared__ __align__(16) u16  xs[6][CHUNK][XPAD];   // bf16 A-operand tiles
    __shared__ __align__(16) u16  hbuf[2][CHUNK][XPAD]; // bf16 h state, double-buffered
    __shared__ float h1_s[DIM];

    const int tid  = threadIdx.x;
    const int b    = blockIdx.x;
    const int g0   = b * CHUNK;
    const int wv   = tid >> 6;          // 0..7
    const int lane = tid & 63;
    const int q    = lane >> 4, nl = lane & 15;
    const int d    = wv * 16 + nl;      // this lane's hidden dim

    auto ldB = [&](const float* B, int mat, int kc, int g) -> s16x8 {
        if (PACKED) {
            return *(const s16x8*)(packed + ((((size_t)mat * 4 + kc) * 32 + (g * 8 + wv)) * 64 + lane) * 8);
        } else {
            int kb = kc * 32 + q * 8;
            int n  = g * 128 + d;
            s16x8 f;
            #pragma unroll
            for (int j = 0; j < 8; j++) f[j] = (short)f2bf(B[(size_t)(kb + j) * FD + n]);
            return f;
        }
    };
    auto load_afrag = [&](const u16* X /* [CHUNK][XPAD] base */, int kc) -> s16x8 {
        return *(const s16x8*)(X + (size_t)nl * XPAD + kc * 32 + q * 8);
    };

    float bzm[4], bzs[4];
    #pragma unroll
    for (int g = 0; g < 4; g++) { bzm[g] = bm[g * 128 + d]; bzs[g] = bs[g * 128 + d]; }

    // ---- layer-invariant LSTM_m t=0: x = empty, h = c = 0 (f32, once per kernel) ----
    float c1, h1;
    {
        float z0 = bzm[0], z1 = bzm[1], z2 = bzm[2], z3 = bzm[3];
        for (int k = 0; k < DIM; k++) {
            float e = empty[k];
            const float* Wr = Wm + (size_t)k * FD + d;
            z0 += e * Wr[0]; z1 += e * Wr[128]; z2 += e * Wr[256]; z3 += e * Wr[384];
        }
        (void)z1;                                   // f-gate irrelevant at c_prev = 0
        c1 = sigm(z0) * tanh_f(z2);                 // gate order i,f,g,o
        h1 = sigm(z3) * tanh_f(c1);
        if (q == 0) h1_s[d] = h1;                   // q==0 lanes cover all 128 dims
    }
    __syncthreads();

    // uh1[g] = (bf16(h1) @ U_m)[g*128+d]
    float uh1[4];
    {
        s16x8 ha[4];
        #pragma unroll
        for (int kc = 0; kc < 4; kc++)
            #pragma unroll
            for (int j = 0; j < 8; j++) ha[kc][j] = (short)f2bf(h1_s[kc * 32 + q * 8 + j]);
        f32x4 acc[4];
        #pragma unroll
        for (int g = 0; g < 4; g++) acc[g] = (f32x4){0.f, 0.f, 0.f, 0.f};
        #pragma unroll
        for (int kc = 0; kc < 4; kc++) {
            #pragma unroll
            for (int g = 0; g < 4; g++) {
                s16x8 u = ldB(Um, 1, kc, g);
                acc[g] = __builtin_amdgcn_mfma_f32_16x16x32_bf16(ha[kc], u, acc[g], 0, 0, 0);
            }
        }
        #pragma unroll
        for (int g = 0; g < 4; g++) uh1[g] = acc[g][0];  // all rows identical
    }

    // gates + store; mode 0: hbuf[parity], 1: xs[0] (h_m), 2: emb (coherent fp32 out)
    auto gates = [&](f32x4* acc, const float* bz, float* cc, int mode, int parity, int l) {
        #pragma unroll
        for (int r2 = 0; r2 < 4; r2++) {
            int m = q * 4 + r2;
            float zi = acc[0][r2] + bz[0];
            float zf = acc[1][r2] + bz[1];
            float zg = acc[2][r2] + bz[2];
            float zo = acc[3][r2] + bz[3];
            float c  = sigm(zf) * cc[r2] + sigm(zi) * tanh_f(zg);
            cc[r2] = c;
            float h  = sigm(zo) * tanh_f(c);
            if (mode == 0)      hbuf[parity][m][d] = f2bf(h);
            else if (mode == 1) xs[0][m][d] = f2bf(h);
            else cstore_f(emb + ((size_t)l * M_NODES + g0 + m) * DIM + d, h);
        }
    };

    for (int l = 1; l < LAYERS; l++) {
        // ---- gather indices (pure inputs) + early-issue rows that predate layer l-1 ----
        f32x4 vv[8];
        size_t gidx = 0; int quarter = 0, slot = 0, node = 0; bool early = false;
        if (tid < 384) {
            quarter = tid & 3;
            int r = tid >> 2;
            slot = r >> 4;
            node = r & 15;
            if (slot < 4) gidx = (size_t)prop_ids [((size_t)l * M_NODES + g0 + node) * 4 + slot];
            else          gidx = (size_t)super_ids[((size_t)l * M_NODES + g0 + node) * 2 + (slot - 4)];
            early = (l == 1) || (gidx < (size_t)(l - 1) * M_NODES);
        }
        // release: this wave's coherent emb stores are through to L3
        asm volatile("s_waitcnt vmcnt(0)" ::: "memory");
        if (tid < 384 && early) {
            const float* src = emb + gidx * DIM + quarter * 32;
            #pragma unroll
            for (int j = 0; j < 8; j++) cload_f4(vv[j], src + j * 4);
        }
        if (l > 1) {   // grid barrier: relaxed agent atomics, NO cache maintenance
            __syncthreads();
            if (tid == 0) {
                __hip_atomic_fetch_add(bar, 1u, __ATOMIC_RELAXED, __HIP_MEMORY_SCOPE_AGENT);
                const unsigned target = (unsigned)(l - 1) * (unsigned)NBLK;
                while (__hip_atomic_load(bar, __ATOMIC_RELAXED, __HIP_MEMORY_SCOPE_AGENT) < target)
                    __builtin_amdgcn_s_sleep(1);
            }
            __syncthreads();
        }
        if (tid < 384 && !early) {     // rows written by layer l-1: load after the barrier
            const float* src = emb + gidx * DIM + quarter * 32;
            #pragma unroll
            for (int j = 0; j < 8; j++) cload_f4(vv[j], src + j * 4);
        }
        asm volatile("s_waitcnt vmcnt(0)" ::: "memory");
        __builtin_amdgcn_sched_barrier(0);
        if (tid < 384) {               // fp32 -> bf16 LDS tiles
            u16* dst = &xs[slot][node][0];
            int e0 = quarter * 32;
            #pragma unroll
            for (int j = 0; j < 8; j++) {
                f32x4 v = vv[j];
                int o = e0 + j * 4;
                dst[o] = f2bf(v[0]); dst[o + 1] = f2bf(v[1]);
                dst[o + 2] = f2bf(v[2]); dst[o + 3] = f2bf(v[3]);
            }
        }
        __syncthreads();

        // ---- Zx precompute: x@W for prop0..3 ----
        f32x4 zxm[4][4];
        {
            s16x8 wf[4][4];
            #pragma unroll
            for (int kc = 0; kc < 4; kc++)
                #pragma unroll
                for (int g = 0; g < 4; g++) wf[kc][g] = ldB(Wm, 0, kc, g);
            #pragma unroll
            for (int s = 0; s < 4; s++) {
                #pragma unroll
                for (int g = 0; g < 4; g++) zxm[s][g] = (f32x4){0.f, 0.f, 0.f, 0.f};
                #pragma unroll
                for (int kc = 0; kc < 4; kc++) {
                    s16x8 a = load_afrag(&xs[s][0][0], kc);
                    #pragma unroll
                    for (int g = 0; g < 4; g++)
                        zxm[s][g] = __builtin_amdgcn_mfma_f32_16x16x32_bf16(a, wf[kc][g], zxm[s][g], 0, 0, 0);
                }
            }
        }

        // ---- recurrent LSTM_m: t=1..4 (t=0 hoisted) ----
        {
            s16x8 uf[4][4];
            #pragma unroll
            for (int kc = 0; kc < 4; kc++)
                #pragma unroll
                for (int g = 0; g < 4; g++) uf[kc][g] = ldB(Um, 1, kc, g);
            float cc[4] = {c1, c1, c1, c1};
            {   // t=1: z = x1@W + h1@U + b, all in registers
                f32x4 acc[4];
                #pragma unroll
                for (int g = 0; g < 4; g++) acc[g] = zxm[0][g] + uh1[g];
                gates(acc, bzm, cc, 0, 1, l);          // write hbuf[1]
            }
            #pragma unroll
            for (int t = 2; t <= 4; t++) {
                __syncthreads();
                const u16* hb = &hbuf[(t - 1) & 1][0][0];
                f32x4 acc[4];
                #pragma unroll
                for (int g = 0; g < 4; g++) acc[g] = zxm[t - 1][g];
                #pragma unroll
                for (int kc = 0; kc < 4; kc++) {
                    s16x8 a = load_afrag(hb, kc);
                    #pragma unroll
                    for (int g = 0; g < 4; g++)
                        acc[g] = __builtin_amdgcn_mfma_f32_16x16x32_bf16(a, uf[kc][g], acc[g], 0, 0, 0);
                }
                if (t < 4) gates(acc, bzm, cc, 0, t & 1, l);
                else       gates(acc, bzm, cc, 1, 0, l);   // h_m -> xs[0]
            }
        }

        // ---- recurrent LSTM_s: seq = [sup0, sup1, h_m] ----
        {
            s16x8 uf[4][4], wf[4][4];
            #pragma unroll
            for (int kc = 0; kc < 4; kc++)
                #pragma unroll
                for (int g = 0; g < 4; g++) {
                    uf[kc][g] = ldB(Us, 3, kc, g);
                    wf[kc][g] = ldB(Ws, 2, kc, g);
                }
            f32x4 acc0[4], zxs1[4];
            #pragma unroll
            for (int g = 0; g < 4; g++) { acc0[g] = (f32x4){0.f,0.f,0.f,0.f}; zxs1[g] = (f32x4){0.f,0.f,0.f,0.f}; }
            #pragma unroll
            for (int kc = 0; kc < 4; kc++) {
                s16x8 a4 = load_afrag(&xs[4][0][0], kc);
                s16x8 a5 = load_afrag(&xs[5][0][0], kc);
                #pragma unroll
                for (int g = 0; g < 4; g++) {
                    acc0[g] = __builtin_amdgcn_mfma_f32_16x16x32_bf16(a4, wf[kc][g], acc0[g], 0, 0, 0);
                    zxs1[g] = __builtin_amdgcn_mfma_f32_16x16x32_bf16(a5, wf[kc][g], zxs1[g], 0, 0, 0);
                }
            }
            float cc[4] = {0.f, 0.f, 0.f, 0.f};
            gates(acc0, bzs, cc, 0, 0, l);             // t=0: h=0, write hbuf[0]
            {   // t=1: x=sup1
                __syncthreads();
                const u16* hb = &hbuf[0][0][0];
                f32x4 acc[4];
                #pragma unroll
                for (int g = 0; g < 4; g++) acc[g] = zxs1[g];
                #pragma unroll
                for (int kc = 0; kc < 4; kc++) {
                    s16x8 a = load_afrag(hb, kc);
                    #pragma unroll
                    for (int g = 0; g < 4; g++)
                        acc[g] = __builtin_amdgcn_mfma_f32_16x16x32_bf16(a, uf[kc][g], acc[g], 0, 0, 0);
                }
                gates(acc, bzs, cc, 0, 1, l);          // write hbuf[1]
            }
            {   // t=2: x=h_m (xs[0])
                __syncthreads();
                const u16* hb = &hbuf[1][0][0];
                f32x4 acc[4];
                #pragma unroll
                for (int g = 0; g < 4; g++) acc[g] = (f32x4){0.f, 0.f, 0.f, 0.f};
                #pragma unroll
                for (int kc = 0; kc < 4; kc++) {
                    s16x8 a  = load_afrag(&xs[0][0][0], kc);
                    s16x8 ah = load_afrag(hb, kc);
                    #pragma unroll
                    for (int g = 0; g < 4; g++) {
                        acc[g] = __builtin_amdgcn_mfma_f32_16x16x32_bf16(a,  wf[kc][g], acc[g], 0, 0, 0);
                        acc[g] = __builtin_amdgcn_mfma_f32_16x16x32_bf16(ah, uf[kc][g], acc[g], 0, 0, 0);
                    }
                }
                gates(acc, bzs, cc, 2, 0, l);          // coherent fp32 layer output
            }
        }
    }
}

// ----------------------------- fallback: proven per-layer kernel -----------------------------
template <bool PACKED>
__global__ __launch_bounds__(TPB, 2) void layer_kernel(
    float* __restrict__ emb, const int* __restrict__ prop_ids, const int* __restrict__ super_ids,
    const float* __restrict__ Wm, const float* __restrict__ Um, const float* __restrict__ bm,
    const float* __restrict__ Ws, const float* __restrict__ Us, const float* __restrict__ bs,
    const float* __restrict__ empty, const u16* __restrict__ packed, int l) {

    __shared__ __align__(16) u16  xs[6][CHUNK][XPAD];
    __shared__ __align__(16) u16  hbuf[2][CHUNK][XPAD];
    __shared__ __align__(16) u16  empty_s[XPAD];

    const int tid  = threadIdx.x;
    const int b    = blockIdx.x;
    const int g0   = b * CHUNK;
    const size_t row0 = (size_t)l * M_NODES + g0;

    const int wv   = tid >> 6;
    const int lane = tid & 63;
    const int q    = lane >> 4, nl = lane & 15;
    const int d    = wv * 16 + nl;

    if (tid < 384) {
        int quarter = tid & 3;
        int r    = tid >> 2;
        int slot = r >> 4;
        int node = r & 15;
        size_t idx;
        if (slot < 4) idx = (size_t)prop_ids [((size_t)l * M_NODES + g0 + node) * 4 + slot];
        else          idx = (size_t)super_ids[((size_t)l * M_NODES + g0 + node) * 2 + (slot - 4)];
        const float4* src = (const float4*)(emb + idx * DIM);
        u16* dst = &xs[slot][node][0];
        int e0 = quarter * 32;
        #pragma unroll
        for (int j = 0; j < 8; j++) {
            float4 v = src[(e0 >> 2) + j];
            int o = e0 + j * 4;
            dst[o] = f2bf(v.x); dst[o + 1] = f2bf(v.y);
            dst[o + 2] = f2bf(v.z); dst[o + 3] = f2bf(v.w);
        }
    } else if (tid < 384 + 128) {
        int dd = tid - 384;
        empty_s[dd] = f2bf(empty[dd]);
    }
    __syncthreads();

    auto load_bfrag_packed = [&](int mat, int kc, int g) -> s16x8 {
        return *(const s16x8*)(packed + ((((size_t)mat * 4 + kc) * 32 + (g * 8 + wv)) * 64 + lane) * 8);
    };
    auto load_bfrag_direct = [&](const float* B, int kc, int g) -> s16x8 {
        int kb = kc * 32 + q * 8;
        int n  = g * 128 + d;
        s16x8 f;
        #pragma unroll
        for (int j = 0; j < 8; j++) f[j] = (short)f2bf(B[(size_t)(kb + j) * FD + n]);
        return f;
    };
    auto load_afrag = [&](const u16* X, int kc) -> s16x8 {
        return *(const s16x8*)(X + (size_t)nl * XPAD + kc * 32 + q * 8);
    };

    auto run_phase = [&](const float* Wg, const float* Ug, const float* bias,
                         int matW, int matU, int nsteps, const int* slots,
                         bool write_hm, bool write_out) {
        s16x8 wf[4][4], uf[4][4];
        #pragma unroll
        for (int kc = 0; kc < 4; kc++) {
            #pragma unroll
            for (int g = 0; g < 4; g++) {
                if (PACKED) { wf[kc][g] = load_bfrag_packed(matW, kc, g);
                              uf[kc][g] = load_bfrag_packed(matU, kc, g); }
                else        { wf[kc][g] = load_bfrag_direct(Wg, kc, g);
                              uf[kc][g] = load_bfrag_direct(Ug, kc, g); }
            }
        }
        float bz[4];
        #pragma unroll
        for (int g = 0; g < 4; g++) bz[g] = bias[g * 128 + d];
        float cc[4] = {0.f, 0.f, 0.f, 0.f};

        #pragma unroll 1
        for (int t = 0; t < nsteps; t++) {
            int s = slots[t];
            f32x4 acc[4];
            #pragma unroll
            for (int g = 0; g < 4; g++) acc[g] = (f32x4){0.f, 0.f, 0.f, 0.f};
            #pragma unroll
            for (int kc = 0; kc < 4; kc++) {
                s16x8 a = (s < 0) ? *(const s16x8*)(&empty_s[kc * 32 + q * 8])
                                  : load_afrag(&xs[s][0][0], kc);
                #pragma unroll
                for (int g = 0; g < 4; g++)
                    acc[g] = __builtin_amdgcn_mfma_f32_16x16x32_bf16(a, wf[kc][g], acc[g], 0, 0, 0);
            }
            if (t > 0) {
                __syncthreads();
                const u16* hb = &hbuf[(t - 1) & 1][0][0];
                #pragma unroll
                for (int kc = 0; kc < 4; kc++) {
                    s16x8 a = load_afrag(hb, kc);
                    #pragma unroll
                    for (int g = 0; g < 4; g++)
                        acc[g] = __builtin_amdgcn_mfma_f32_16x16x32_bf16(a, uf[kc][g], acc[g], 0, 0, 0);
                }
            }
            bool last = (t == nsteps - 1);
            #pragma unroll
            for (int r2 = 0; r2 < 4; r2++) {
                int m = q * 4 + r2;
                float zi = acc[0][r2] + bz[0];
                float zf = acc[1][r2] + bz[1];
                float zg = acc[2][r2] + bz[2];
                float zo = acc[3][r2] + bz[3];
                float c  = sigm(zf) * cc[r2] + sigm(zi) * tanh_f(zg);
                cc[r2] = c;
                float h  = sigm(zo) * tanh_f(c);
                if (!last)          hbuf[t & 1][m][d] = f2bf(h);
                else if (write_hm)  xs[0][m][d] = f2bf(h);
                else if (write_out) emb[(row0 + m) * DIM + d] = h;
            }
        }
    };

    {
        const int slots_m[5] = {-1, 0, 1, 2, 3};
        run_phase(Wm, Um, bm, 0, 1, 5, slots_m, true, false);
    }
    {
        const int slots_s[3] = {4, 5, 0};
        run_phase(Ws, Us, bs, 2, 3, 3, slots_s, false, true);
    }
}

extern "C" void kernel_launch(void* const* d_in, const int* in_sizes, int n_in,
                              void* d_out, int out_size, void* d_ws, size_t ws_size,
                              hipStream_t stream) {
    const int*   names = (const int*)d_in[0];
    const int*   pids  = (const int*)d_in[1];
    const int*   sids  = (const int*)d_in[2];
    const float* table = (const float*)d_in[3];
    const float* Wm    = (const float*)d_in[4];
    const float* Um    = (const float*)d_in[5];
    const float* bm    = (const float*)d_in[6];
    const float* Ws    = (const float*)d_in[7];
    const float* Us    = (const float*)d_in[8];
    const float* bs    = (const float*)d_in[9];
    const float* empt  = (const float*)d_in[10];
    float* emb  = (float*)d_out;
    u16* packed = (u16*)d_ws;

    l0_kernel<<<256, 256, 0, stream>>>(names, table, emb);

    const size_t packed_bytes = (size_t)4 * 4 * 32 * 64 * 8 * sizeof(u16);  // 512 KB
    const bool ws_ok = ws_size >= packed_bytes + 64;

    if (ws_ok) {
        unsigned* bar = (unsigned*)((char*)d_ws + packed_bytes);
        repack_kernel<<<128, 256, 0, stream>>>(Wm, Um, Ws, Us, packed, bar);

        void* args[] = {(void*)&emb, (void*)&pids, (void*)&sids, (void*)&Wm, (void*)&Um, (void*)&bm,
                        (void*)&Ws, (void*)&Us, (void*)&bs, (void*)&empt, (void*)&packed, (void*)&bar};
        void (*kptr)(float*, const int*, const int*, const float*, const float*, const float*,
                     const float*, const float*, const float*, const float*, const u16*, unsigned*) =
            fused_kernel<true>;
        hipError_t err = hipLaunchCooperativeKernel((const void*)kptr, dim3(NBLK), dim3(TPB),
                                                    args, 0, stream);
        if (err == hipSuccess) return;
        // coop launch failed -> proven per-layer path (packed)
        for (int l = 1; l < LAYERS; l++)
            layer_kernel<true><<<NBLK, TPB, 0, stream>>>(emb, pids, sids, Wm, Um, bm,
                                                         Ws, Us, bs, empt, packed, l);
    } else {
        for (int l = 1; l < LAYERS; l++)
            layer_kernel<false><<<NBLK, TPB, 0, stream>>>(emb, pids, sids, Wm, Um, bm,
                                                          Ws, Us, bs, empt, packed, l);
    }
}

// Round 3
// 1983.371 us; speedup vs baseline: 1.8811x; 1.1145x over previous
//
#include <hip/hip_runtime.h>

typedef unsigned short u16;
typedef short s16x8 __attribute__((ext_vector_type(8)));
typedef float f32x4 __attribute__((ext_vector_type(4)));

#define LAYERS   64
#define M_NODES  2048
#define DIM      128
#define FD       512
#define CHUNK    16
#define NBLK     128     // M_NODES / CHUNK
#define TPB      512     // 8 waves; wave wv owns hidden dims [wv*16, wv*16+16)
#define XPAD     136     // 128 + 8 pad u16 (16B-aligned rows)

__device__ __forceinline__ u16 f2bf(float f) {
    union { float f; unsigned int i; } v; v.f = f;
    unsigned int r = (v.i + 0x7FFFu + ((v.i >> 16) & 1u)) >> 16;
    return (u16)r;
}
__device__ __forceinline__ float sigm(float x) {
    return __builtin_amdgcn_rcpf(1.0f + __builtin_exp2f(-1.44269504f * x));
}
__device__ __forceinline__ float tanh_f(float x) {
    float ax = __builtin_fabsf(x);
    float t  = __builtin_exp2f(-2.88539008f * ax);   // exp(-2|x|)
    float r  = (1.0f - t) * __builtin_amdgcn_rcpf(1.0f + t);
    return __builtin_copysignf(r, x);
}

// write-through store to the coherence point (L3); readers on any XCD see it after vmcnt ACK
__device__ __forceinline__ void cstore_f(float* p, float v) {
    asm volatile("global_store_dword %0, %1, off sc0 sc1" :: "v"(p), "v"(v) : "memory");
}

// ---------------- layer 0: emb[m] = basic_table[basic_names[m]]  (fp32 copy) ----------------
__global__ void l0_kernel(const int* __restrict__ names, const float* __restrict__ table,
                          float* __restrict__ emb) {
    int v = blockIdx.x * blockDim.x + threadIdx.x;      // 2048 rows * 32 float4
    if (v >= M_NODES * (DIM / 4)) return;
    int row = v >> 5, c = v & 31;
    const float4* src = (const float4*)(table + (size_t)names[row] * DIM);
    ((float4*)(emb + (size_t)row * DIM))[c] = src[c];
}

// ------------- repack W_m,U_m,W_s,U_s (fp32) into bf16 MFMA B-fragments in d_ws -------------
__global__ void repack_kernel(const float* __restrict__ Wm, const float* __restrict__ Um,
                              const float* __restrict__ Ws, const float* __restrict__ Us,
                              u16* __restrict__ packed, unsigned* __restrict__ flags) {
    int t = blockIdx.x * blockDim.x + threadIdx.x;      // 4*4*32*64 = 32768 threads
    if (t < NBLK) flags[t] = 0;                         // progress flags reset (per graph run)
    if (t >= 4 * 4 * 32 * 64) return;
    int lane = t & 63, ntg = (t >> 6) & 31, kc = (t >> 11) & 3, mat = t >> 13;
    const float* B = (mat == 0) ? Wm : (mat == 1) ? Um : (mat == 2) ? Ws : Us;
    int q = lane >> 4, nl = lane & 15;
    int kb = kc * 32 + q * 8;
    int n  = ntg * 16 + nl;
    u16* dst = packed + ((((size_t)mat * 4 + kc) * 32 + ntg) * 64 + lane) * 8;
    #pragma unroll
    for (int j = 0; j < 8; j++) dst[j] = f2bf(B[(size_t)(kb + j) * FD + n]);
}

// ======================= persistent fused kernel: all 63 layers, one launch =======================
// NO global barrier: per-block progress flags (flags[b] = l  <=>  block b's layer l-1 emb rows are
// ACKed at L3). Each gather lane needing a layer-(l-1) row spins only on that row's writer block.
// emb stores are write-through (sc0 sc1 -> L3); gather loads are NORMAL cached loads (safe: rows
// are write-once via L2-bypassing stores, and dispatch-start acquire killed any pre-kernel lines).
// Um fragments are register-resident for all 63 layers; Wm prefetched before the dependency spins.
__global__ __launch_bounds__(TPB, 2) void fused_kernel(
    float* __restrict__ emb, const int* __restrict__ prop_ids, const int* __restrict__ super_ids,
    const float* __restrict__ Wm, const float* __restrict__ Um, const float* __restrict__ bm,
    const float* __restrict__ Ws, const float* __restrict__ Us, const float* __restrict__ bs,
    const float* __restrict__ empty, const u16* __restrict__ packed, unsigned* __restrict__ flags) {

    // slots 0..3: prop embeddings (slot 0 reused for h_m); slots 4..5: super embeddings
    __shared__ __align__(16) u16  xs[6][CHUNK][XPAD];   // bf16 A-operand tiles
    __shared__ __align__(16) u16  hbuf[2][CHUNK][XPAD]; // bf16 h state, double-buffered
    __shared__ float h1_s[DIM];

    const int tid  = threadIdx.x;
    const int b    = blockIdx.x;
    const int g0   = b * CHUNK;
    const int wv   = tid >> 6;          // 0..7
    const int lane = tid & 63;
    const int q    = lane >> 4, nl = lane & 15;
    const int d    = wv * 16 + nl;      // this lane's hidden dim

    auto ldB = [&](int mat, int kc, int g) -> s16x8 {
        return *(const s16x8*)(packed + ((((size_t)mat * 4 + kc) * 32 + (g * 8 + wv)) * 64 + lane) * 8);
    };
    auto load_afrag = [&](const u16* X /* [CHUNK][XPAD] base */, int kc) -> s16x8 {
        return *(const s16x8*)(X + (size_t)nl * XPAD + kc * 32 + q * 8);
    };

    float bzm[4], bzs[4];
    #pragma unroll
    for (int g = 0; g < 4; g++) { bzm[g] = bm[g * 128 + d]; bzs[g] = bs[g * 128 + d]; }

    // ---- Um fragments: register-resident for the whole kernel (64 VGPRs) ----
    s16x8 ufm[4][4];
    #pragma unroll
    for (int kc = 0; kc < 4; kc++)
        #pragma unroll
        for (int g = 0; g < 4; g++) ufm[kc][g] = ldB(1, kc, g);

    // ---- layer-invariant LSTM_m t=0: x = empty, h = c = 0 (f32, once per kernel) ----
    float c1, h1;
    {
        float z0 = bzm[0], z1 = bzm[1], z2 = bzm[2], z3 = bzm[3];
        for (int k = 0; k < DIM; k++) {
            float e = empty[k];
            const float* Wr = Wm + (size_t)k * FD + d;
            z0 += e * Wr[0]; z1 += e * Wr[128]; z2 += e * Wr[256]; z3 += e * Wr[384];
        }
        (void)z1;                                   // f-gate irrelevant at c_prev = 0
        c1 = sigm(z0) * tanh_f(z2);                 // gate order i,f,g,o
        h1 = sigm(z3) * tanh_f(c1);
        if (q == 0) h1_s[d] = h1;                   // q==0 lanes cover all 128 dims
    }
    __syncthreads();

    // uh1[g] = (bf16(h1) @ U_m)[g*128+d]
    float uh1[4];
    {
        s16x8 ha[4];
        #pragma unroll
        for (int kc = 0; kc < 4; kc++)
            #pragma unroll
            for (int j = 0; j < 8; j++) ha[kc][j] = (short)f2bf(h1_s[kc * 32 + q * 8 + j]);
        f32x4 acc[4];
        #pragma unroll
        for (int g = 0; g < 4; g++) acc[g] = (f32x4){0.f, 0.f, 0.f, 0.f};
        #pragma unroll
        for (int kc = 0; kc < 4; kc++) {
            #pragma unroll
            for (int g = 0; g < 4; g++)
                acc[g] = __builtin_amdgcn_mfma_f32_16x16x32_bf16(ha[kc], ufm[kc][g], acc[g], 0, 0, 0);
        }
        #pragma unroll
        for (int g = 0; g < 4; g++) uh1[g] = acc[g][0];  // all rows identical
    }

    // gates + store; mode 0: hbuf[parity], 1: xs[0] (h_m), 2: emb (coherent fp32 out)
    auto gates = [&](f32x4* acc, const float* bz, float* cc, int mode, int parity, int l) {
        #pragma unroll
        for (int r2 = 0; r2 < 4; r2++) {
            int m = q * 4 + r2;
            float zi = acc[0][r2] + bz[0];
            float zf = acc[1][r2] + bz[1];
            float zg = acc[2][r2] + bz[2];
            float zo = acc[3][r2] + bz[3];
            float c  = sigm(zf) * cc[r2] + sigm(zi) * tanh_f(zg);
            cc[r2] = c;
            float h  = sigm(zo) * tanh_f(c);
            if (mode == 0)      hbuf[parity][m][d] = f2bf(h);
            else if (mode == 1) xs[0][m][d] = f2bf(h);
            else cstore_f(emb + ((size_t)l * M_NODES + g0 + m) * DIM + d, h);
        }
    };

    #pragma unroll 1
    for (int l = 1; l < LAYERS; l++) {
        // ---- gather indices (pure inputs) ----
        const bool isg = (tid < 384);
        int quarter = 0, slot = 0, node = 0, wb = 0; size_t gidx = 0; bool late = false;
        if (isg) {
            quarter = tid & 3;
            int r = tid >> 2;
            slot = r >> 4;
            node = r & 15;
            if (slot < 4) gidx = (size_t)prop_ids [((size_t)l * M_NODES + g0 + node) * 4 + slot];
            else          gidx = (size_t)super_ids[((size_t)l * M_NODES + g0 + node) * 2 + (slot - 4)];
            wb   = (int)((gidx & (size_t)(M_NODES - 1)) >> 4);   // writer block of this row
            late = (l > 1) && (gidx >= (size_t)(l - 1) * M_NODES) && (wb != b);
        }
        // release: all waves drain their layer-(l-1) emb stores, then publish progress
        asm volatile("s_waitcnt vmcnt(0)" ::: "memory");
        __syncthreads();                        // also protects xs/hbuf reuse across layers
        if (l > 1 && tid == 0)
            __hip_atomic_store(&flags[b], (unsigned)l, __ATOMIC_RELAXED, __HIP_MEMORY_SCOPE_AGENT);

        // ---- early gather (rows older than layer l-1, or own rows): issue immediately ----
        f32x4 vv[8];
        const f32x4* src = (const f32x4*)(emb + gidx * DIM) + quarter * 8;
        if (isg && !late) {
            #pragma unroll
            for (int j = 0; j < 8; j++) vv[j] = src[j];
        }
        // ---- Wm prefetch (immutable, L2-hot): overlaps the dependency spins ----
        s16x8 wfm[4][4];
        #pragma unroll
        for (int kc = 0; kc < 4; kc++)
            #pragma unroll
            for (int g = 0; g < 4; g++) wfm[kc][g] = ldB(0, kc, g);
        // ---- late rows: spin on the writer block's flag, then load ----
        if (late) {
            while (__hip_atomic_load(&flags[wb], __ATOMIC_RELAXED, __HIP_MEMORY_SCOPE_AGENT)
                   < (unsigned)l)
                __builtin_amdgcn_s_sleep(2);
        }
        asm volatile("" ::: "memory");          // no load hoisting above the spin
        if (late) {
            #pragma unroll
            for (int j = 0; j < 8; j++) vv[j] = src[j];
        }
        // ---- fp32 -> bf16 LDS tiles (8B vector writes) ----
        if (isg) {
            u16* dst = &xs[slot][node][0];
            int e0 = quarter * 32;
            #pragma unroll
            for (int j = 0; j < 8; j++) {
                f32x4 v = vv[j];
                ushort4 w;
                w.x = f2bf(v[0]); w.y = f2bf(v[1]); w.z = f2bf(v[2]); w.w = f2bf(v[3]);
                *(ushort4*)(dst + e0 + j * 4) = w;
            }
        }
        __syncthreads();

        // ---- Zx precompute: x@W for prop0..3 ----
        f32x4 zxm[4][4];
        #pragma unroll
        for (int s = 0; s < 4; s++) {
            #pragma unroll
            for (int g = 0; g < 4; g++) zxm[s][g] = (f32x4){0.f, 0.f, 0.f, 0.f};
            #pragma unroll
            for (int kc = 0; kc < 4; kc++) {
                s16x8 a = load_afrag(&xs[s][0][0], kc);
                #pragma unroll
                for (int g = 0; g < 4; g++)
                    zxm[s][g] = __builtin_amdgcn_mfma_f32_16x16x32_bf16(a, wfm[kc][g], zxm[s][g], 0, 0, 0);
            }
        }

        // ---- recurrent LSTM_m: t=1..4 (t=0 hoisted; Um resident) ----
        {
            float cc[4] = {c1, c1, c1, c1};
            {   // t=1: z = x1@W + h1@U + b, all in registers
                f32x4 acc[4];
                #pragma unroll
                for (int g = 0; g < 4; g++) acc[g] = zxm[0][g] + uh1[g];
                gates(acc, bzm, cc, 0, 1, l);          // write hbuf[1]
            }
            #pragma unroll
            for (int t = 2; t <= 4; t++) {
                __syncthreads();
                const u16* hb = &hbuf[(t - 1) & 1][0][0];
                f32x4 acc[4];
                #pragma unroll
                for (int g = 0; g < 4; g++) acc[g] = zxm[t - 1][g];
                #pragma unroll
                for (int kc = 0; kc < 4; kc++) {
                    s16x8 a = load_afrag(hb, kc);
                    #pragma unroll
                    for (int g = 0; g < 4; g++)
                        acc[g] = __builtin_amdgcn_mfma_f32_16x16x32_bf16(a, ufm[kc][g], acc[g], 0, 0, 0);
                }
                if (t < 4) gates(acc, bzm, cc, 0, t & 1, l);
                else       gates(acc, bzm, cc, 1, 0, l);   // h_m -> xs[0]
            }
        }

        // ---- recurrent LSTM_s: seq = [sup0, sup1, h_m] ----
        {
            s16x8 ufs[4][4], wfs[4][4];
            #pragma unroll
            for (int kc = 0; kc < 4; kc++)
                #pragma unroll
                for (int g = 0; g < 4; g++) {
                    ufs[kc][g] = ldB(3, kc, g);
                    wfs[kc][g] = ldB(2, kc, g);
                }
            f32x4 acc0[4], zxs1[4];
            #pragma unroll
            for (int g = 0; g < 4; g++) { acc0[g] = (f32x4){0.f,0.f,0.f,0.f}; zxs1[g] = (f32x4){0.f,0.f,0.f,0.f}; }
            #pragma unroll
            for (int kc = 0; kc < 4; kc++) {
                s16x8 a4 = load_afrag(&xs[4][0][0], kc);
                s16x8 a5 = load_afrag(&xs[5][0][0], kc);
                #pragma unroll
                for (int g = 0; g < 4; g++) {
                    acc0[g] = __builtin_amdgcn_mfma_f32_16x16x32_bf16(a4, wfs[kc][g], acc0[g], 0, 0, 0);
                    zxs1[g] = __builtin_amdgcn_mfma_f32_16x16x32_bf16(a5, wfs[kc][g], zxs1[g], 0, 0, 0);
                }
            }
            float cc[4] = {0.f, 0.f, 0.f, 0.f};
            gates(acc0, bzs, cc, 0, 0, l);             // t=0: h=0, write hbuf[0]
            {   // t=1: x=sup1
                __syncthreads();
                const u16* hb = &hbuf[0][0][0];
                f32x4 acc[4];
                #pragma unroll
                for (int g = 0; g < 4; g++) acc[g] = zxs1[g];
                #pragma unroll
                for (int kc = 0; kc < 4; kc++) {
                    s16x8 a = load_afrag(hb, kc);
                    #pragma unroll
                    for (int g = 0; g < 4; g++)
                        acc[g] = __builtin_amdgcn_mfma_f32_16x16x32_bf16(a, ufs[kc][g], acc[g], 0, 0, 0);
                }
                gates(acc, bzs, cc, 0, 1, l);          // write hbuf[1]
            }
            {   // t=2: x=h_m (xs[0])
                __syncthreads();
                const u16* hb = &hbuf[1][0][0];
                f32x4 acc[4];
                #pragma unroll
                for (int g = 0; g < 4; g++) acc[g] = (f32x4){0.f, 0.f, 0.f, 0.f};
                #pragma unroll
                for (int kc = 0; kc < 4; kc++) {
                    s16x8 a  = load_afrag(&xs[0][0][0], kc);
                    s16x8 ah = load_afrag(hb, kc);
                    #pragma unroll
                    for (int g = 0; g < 4; g++) {
                        acc[g] = __builtin_amdgcn_mfma_f32_16x16x32_bf16(a,  wfs[kc][g], acc[g], 0, 0, 0);
                        acc[g] = __builtin_amdgcn_mfma_f32_16x16x32_bf16(ah, ufs[kc][g], acc[g], 0, 0, 0);
                    }
                }
                gates(acc, bzs, cc, 2, 0, l);          // coherent fp32 layer output
            }
        }
    }
}

// ----------------------------- fallback: proven per-layer kernel -----------------------------
template <bool PACKED>
__global__ __launch_bounds__(TPB, 2) void layer_kernel(
    float* __restrict__ emb, const int* __restrict__ prop_ids, const int* __restrict__ super_ids,
    const float* __restrict__ Wm, const float* __restrict__ Um, const float* __restrict__ bm,
    const float* __restrict__ Ws, const float* __restrict__ Us, const float* __restrict__ bs,
    const float* __restrict__ empty, const u16* __restrict__ packed, int l) {

    __shared__ __align__(16) u16  xs[6][CHUNK][XPAD];
    __shared__ __align__(16) u16  hbuf[2][CHUNK][XPAD];
    __shared__ __align__(16) u16  empty_s[XPAD];

    const int tid  = threadIdx.x;
    const int b    = blockIdx.x;
    const int g0   = b * CHUNK;
    const size_t row0 = (size_t)l * M_NODES + g0;

    const int wv   = tid >> 6;
    const int lane = tid & 63;
    const int q    = lane >> 4, nl = lane & 15;
    const int d    = wv * 16 + nl;

    if (tid < 384) {
        int quarter = tid & 3;
        int r    = tid >> 2;
        int slot = r >> 4;
        int node = r & 15;
        size_t idx;
        if (slot < 4) idx = (size_t)prop_ids [((size_t)l * M_NODES + g0 + node) * 4 + slot];
        else          idx = (size_t)super_ids[((size_t)l * M_NODES + g0 + node) * 2 + (slot - 4)];
        const float4* src = (const float4*)(emb + idx * DIM);
        u16* dst = &xs[slot][node][0];
        int e0 = quarter * 32;
        #pragma unroll
        for (int j = 0; j < 8; j++) {
            float4 v = src[(e0 >> 2) + j];
            int o = e0 + j * 4;
            dst[o] = f2bf(v.x); dst[o + 1] = f2bf(v.y);
            dst[o + 2] = f2bf(v.z); dst[o + 3] = f2bf(v.w);
        }
    } else if (tid < 384 + 128) {
        int dd = tid - 384;
        empty_s[dd] = f2bf(empty[dd]);
    }
    __syncthreads();

    auto load_bfrag_packed = [&](int mat, int kc, int g) -> s16x8 {
        return *(const s16x8*)(packed + ((((size_t)mat * 4 + kc) * 32 + (g * 8 + wv)) * 64 + lane) * 8);
    };
    auto load_bfrag_direct = [&](const float* B, int kc, int g) -> s16x8 {
        int kb = kc * 32 + q * 8;
        int n  = g * 128 + d;
        s16x8 f;
        #pragma unroll
        for (int j = 0; j < 8; j++) f[j] = (short)f2bf(B[(size_t)(kb + j) * FD + n]);
        return f;
    };
    auto load_afrag = [&](const u16* X, int kc) -> s16x8 {
        return *(const s16x8*)(X + (size_t)nl * XPAD + kc * 32 + q * 8);
    };

    auto run_phase = [&](const float* Wg, const float* Ug, const float* bias,
                         int matW, int matU, int nsteps, const int* slots,
                         bool write_hm, bool write_out) {
        s16x8 wf[4][4], uf[4][4];
        #pragma unroll
        for (int kc = 0; kc < 4; kc++) {
            #pragma unroll
            for (int g = 0; g < 4; g++) {
                if (PACKED) { wf[kc][g] = load_bfrag_packed(matW, kc, g);
                              uf[kc][g] = load_bfrag_packed(matU, kc, g); }
                else        { wf[kc][g] = load_bfrag_direct(Wg, kc, g);
                              uf[kc][g] = load_bfrag_direct(Ug, kc, g); }
            }
        }
        float bz[4];
        #pragma unroll
        for (int g = 0; g < 4; g++) bz[g] = bias[g * 128 + d];
        float cc[4] = {0.f, 0.f, 0.f, 0.f};

        #pragma unroll 1
        for (int t = 0; t < nsteps; t++) {
            int s = slots[t];
            f32x4 acc[4];
            #pragma unroll
            for (int g = 0; g < 4; g++) acc[g] = (f32x4){0.f, 0.f, 0.f, 0.f};
            #pragma unroll
            for (int kc = 0; kc < 4; kc++) {
                s16x8 a = (s < 0) ? *(const s16x8*)(&empty_s[kc * 32 + q * 8])
                                  : load_afrag(&xs[s][0][0], kc);
                #pragma unroll
                for (int g = 0; g < 4; g++)
                    acc[g] = __builtin_amdgcn_mfma_f32_16x16x32_bf16(a, wf[kc][g], acc[g], 0, 0, 0);
            }
            if (t > 0) {
                __syncthreads();
                const u16* hb = &hbuf[(t - 1) & 1][0][0];
                #pragma unroll
                for (int kc = 0; kc < 4; kc++) {
                    s16x8 a = load_afrag(hb, kc);
                    #pragma unroll
                    for (int g = 0; g < 4; g++)
                        acc[g] = __builtin_amdgcn_mfma_f32_16x16x32_bf16(a, uf[kc][g], acc[g], 0, 0, 0);
                }
            }
            bool last = (t == nsteps - 1);
            #pragma unroll
            for (int r2 = 0; r2 < 4; r2++) {
                int m = q * 4 + r2;
                float zi = acc[0][r2] + bz[0];
                float zf = acc[1][r2] + bz[1];
                float zg = acc[2][r2] + bz[2];
                float zo = acc[3][r2] + bz[3];
                float c  = sigm(zf) * cc[r2] + sigm(zi) * tanh_f(zg);
                cc[r2] = c;
                float h  = sigm(zo) * tanh_f(c);
                if (!last)          hbuf[t & 1][m][d] = f2bf(h);
                else if (write_hm)  xs[0][m][d] = f2bf(h);
                else if (write_out) emb[(row0 + m) * DIM + d] = h;
            }
        }
    };

    {
        const int slots_m[5] = {-1, 0, 1, 2, 3};
        run_phase(Wm, Um, bm, 0, 1, 5, slots_m, true, false);
    }
    {
        const int slots_s[3] = {4, 5, 0};
        run_phase(Ws, Us, bs, 2, 3, 3, slots_s, false, true);
    }
}

extern "C" void kernel_launch(void* const* d_in, const int* in_sizes, int n_in,
                              void* d_out, int out_size, void* d_ws, size_t ws_size,
                              hipStream_t stream) {
    const int*   names = (const int*)d_in[0];
    const int*   pids  = (const int*)d_in[1];
    const int*   sids  = (const int*)d_in[2];
    const float* table = (const float*)d_in[3];
    const float* Wm    = (const float*)d_in[4];
    const float* Um    = (const float*)d_in[5];
    const float* bm    = (const float*)d_in[6];
    const float* Ws    = (const float*)d_in[7];
    const float* Us    = (const float*)d_in[8];
    const float* bs    = (const float*)d_in[9];
    const float* empt  = (const float*)d_in[10];
    float* emb  = (float*)d_out;
    u16* packed = (u16*)d_ws;

    l0_kernel<<<256, 256, 0, stream>>>(names, table, emb);

    const size_t packed_bytes = (size_t)4 * 4 * 32 * 64 * 8 * sizeof(u16);  // 512 KB
    const bool ws_ok = ws_size >= packed_bytes + NBLK * sizeof(unsigned);

    if (ws_ok) {
        unsigned* flags = (unsigned*)((char*)d_ws + packed_bytes);
        repack_kernel<<<128, 256, 0, stream>>>(Wm, Um, Ws, Us, packed, flags);

        void* args[] = {(void*)&emb, (void*)&pids, (void*)&sids, (void*)&Wm, (void*)&Um, (void*)&bm,
                        (void*)&Ws, (void*)&Us, (void*)&bs, (void*)&empt, (void*)&packed, (void*)&flags};
        void (*kptr)(float*, const int*, const int*, const float*, const float*, const float*,
                     const float*, const float*, const float*, const float*, const u16*, unsigned*) =
            fused_kernel;
        hipError_t err = hipLaunchCooperativeKernel((const void*)kptr, dim3(NBLK), dim3(TPB),
                                                    args, 0, stream);
        if (err == hipSuccess) return;
        // coop launch failed -> proven per-layer path (packed)
        for (int l = 1; l < LAYERS; l++)
            layer_kernel<true><<<NBLK, TPB, 0, stream>>>(emb, pids, sids, Wm, Um, bm,
                                                         Ws, Us, bs, empt, packed, l);
    } else {
        for (int l = 1; l < LAYERS; l++)
            layer_kernel<false><<<NBLK, TPB, 0, stream>>>(emb, pids, sids, Wm, Um, bm,
                                                          Ws, Us, bs, empt, packed, l);
    }
}

// Round 4
// 1601.565 us; speedup vs baseline: 2.3296x; 1.2384x over previous
//
#include <hip/hip_runtime.h>

typedef unsigned short u16;
typedef short s16x8 __attribute__((ext_vector_type(8)));
typedef float f32x4 __attribute__((ext_vector_type(4)));

#define LAYERS   64
#define M_NODES  2048
#define DIM      128
#define FD       512
#define CHUNK    16
#define NBLK     128     // M_NODES / CHUNK
#define TPB      512     // 8 waves; wave wv owns hidden dims [wv*16, wv*16+16)
#define XPAD     136     // 128 + 8 pad u16 (16B-aligned rows)
#define FLAGP    4       // flag padding: 16 B per flag (own cache slot)

__device__ __forceinline__ u16 f2bf(float f) {
    union { float f; unsigned int i; } v; v.f = f;
    unsigned int r = (v.i + 0x7FFFu + ((v.i >> 16) & 1u)) >> 16;
    return (u16)r;
}
__device__ __forceinline__ float sigm(float x) {
    return __builtin_amdgcn_rcpf(1.0f + __builtin_exp2f(-1.44269504f * x));
}
__device__ __forceinline__ float tanh_f(float x) {
    float ax = __builtin_fabsf(x);
    float t  = __builtin_exp2f(-2.88539008f * ax);   // exp(-2|x|)
    float r  = (1.0f - t) * __builtin_amdgcn_rcpf(1.0f + t);
    return __builtin_copysignf(r, x);
}

// write-through store to the coherence point (L3); readers on any XCD see it after vmcnt ACK
__device__ __forceinline__ void cstore_f(float* p, float v) {
    asm volatile("global_store_dword %0, %1, off sc0 sc1" :: "v"(p), "v"(v) : "memory");
}

// ---------------- layer 0: emb[m] = basic_table[basic_names[m]]  (fp32 copy) ----------------
__global__ void l0_kernel(const int* __restrict__ names, const float* __restrict__ table,
                          float* __restrict__ emb) {
    int v = blockIdx.x * blockDim.x + threadIdx.x;      // 2048 rows * 32 float4
    if (v >= M_NODES * (DIM / 4)) return;
    int row = v >> 5, c = v & 31;
    const float4* src = (const float4*)(table + (size_t)names[row] * DIM);
    ((float4*)(emb + (size_t)row * DIM))[c] = src[c];
}

// ------------- repack W_m,U_m,W_s,U_s (fp32) into bf16 MFMA B-fragments in d_ws -------------
__global__ void repack_kernel(const float* __restrict__ Wm, const float* __restrict__ Um,
                              const float* __restrict__ Ws, const float* __restrict__ Us,
                              u16* __restrict__ packed, unsigned* __restrict__ flags) {
    int t = blockIdx.x * blockDim.x + threadIdx.x;      // 4*4*32*64 = 32768 threads
    if (t < NBLK * FLAGP) flags[t] = 0;                 // progress flags reset (per graph run)
    if (t >= 4 * 4 * 32 * 64) return;
    int lane = t & 63, ntg = (t >> 6) & 31, kc = (t >> 11) & 3, mat = t >> 13;
    const float* B = (mat == 0) ? Wm : (mat == 1) ? Um : (mat == 2) ? Ws : Us;
    int q = lane >> 4, nl = lane & 15;
    int kb = kc * 32 + q * 8;
    int n  = ntg * 16 + nl;
    u16* dst = packed + ((((size_t)mat * 4 + kc) * 32 + ntg) * 64 + lane) * 8;
    #pragma unroll
    for (int j = 0; j < 8; j++) dst[j] = f2bf(B[(size_t)(kb + j) * FD + n]);
}

// ======================= persistent fused kernel: all 63 layers, one launch =======================
// launch_bounds(TPB,1): 256-VGPR budget (the (TPB,2) cap at 128 caused heavy scratch spilling; the
// 128-block grid never had 2 blocks/CU anyway). Sync: per-block progress flags, SAFE protocol:
// row of layer gl from writer wb is readable iff gl==0 (l0_kernel done) or wb==b or flags[wb]>=gl+1
// (checked per row — fixes r3's latent race on rows older than l-1 from lagging writers).
// emb stores write-through (sc0 sc1 -> L3); gather loads normal-cached (safe: rows write-once via
// L2-bypassing stores; all reads flag-gated => no stale L2 lines ever allocated).
__global__ __launch_bounds__(TPB, 1) void fused_kernel(
    float* __restrict__ emb, const int* __restrict__ prop_ids, const int* __restrict__ super_ids,
    const float* __restrict__ Wm, const float* __restrict__ Um, const float* __restrict__ bm,
    const float* __restrict__ Ws, const float* __restrict__ Us, const float* __restrict__ bs,
    const float* __restrict__ empty, const u16* __restrict__ packed, unsigned* __restrict__ flags) {

    // slots 0..3: prop embeddings (slot 0 reused for h_m); slots 4..5: super embeddings
    __shared__ __align__(16) u16  xs[6][CHUNK][XPAD];   // bf16 A-operand tiles
    __shared__ __align__(16) u16  hbuf[2][CHUNK][XPAD]; // bf16 h state, double-buffered
    __shared__ float h1_s[DIM];

    const int tid  = threadIdx.x;
    const int b    = blockIdx.x;
    const int g0   = b * CHUNK;
    const int wv   = tid >> 6;          // 0..7
    const int lane = tid & 63;
    const int q    = lane >> 4, nl = lane & 15;
    const int d    = wv * 16 + nl;      // this lane's hidden dim

    auto ldB = [&](int mat, int kc, int g) -> s16x8 {
        return *(const s16x8*)(packed + ((((size_t)mat * 4 + kc) * 32 + (g * 8 + wv)) * 64 + lane) * 8);
    };
    auto load_afrag = [&](const u16* X /* [CHUNK][XPAD] base */, int kc) -> s16x8 {
        return *(const s16x8*)(X + (size_t)nl * XPAD + kc * 32 + q * 8);
    };

    float bzm[4], bzs[4];
    #pragma unroll
    for (int g = 0; g < 4; g++) { bzm[g] = bm[g * 128 + d]; bzs[g] = bs[g * 128 + d]; }

    // ---- layer-invariant LSTM_m t=0: x = empty, h = c = 0 (f32, once per kernel) ----
    float c1, h1;
    {
        float z0 = bzm[0], z1 = bzm[1], z2 = bzm[2], z3 = bzm[3];
        for (int k = 0; k < DIM; k++) {
            float e = empty[k];
            const float* Wr = Wm + (size_t)k * FD + d;
            z0 += e * Wr[0]; z1 += e * Wr[128]; z2 += e * Wr[256]; z3 += e * Wr[384];
        }
        (void)z1;                                   // f-gate irrelevant at c_prev = 0
        c1 = sigm(z0) * tanh_f(z2);                 // gate order i,f,g,o
        h1 = sigm(z3) * tanh_f(c1);
        if (q == 0) h1_s[d] = h1;                   // q==0 lanes cover all 128 dims
    }
    __syncthreads();

    // uh1[g] = (bf16(h1) @ U_m)[g*128+d]
    float uh1[4];
    {
        s16x8 ha[4];
        #pragma unroll
        for (int kc = 0; kc < 4; kc++)
            #pragma unroll
            for (int j = 0; j < 8; j++) ha[kc][j] = (short)f2bf(h1_s[kc * 32 + q * 8 + j]);
        f32x4 acc[4];
        #pragma unroll
        for (int g = 0; g < 4; g++) acc[g] = (f32x4){0.f, 0.f, 0.f, 0.f};
        #pragma unroll
        for (int kc = 0; kc < 4; kc++) {
            #pragma unroll
            for (int g = 0; g < 4; g++) {
                s16x8 u = ldB(1, kc, g);
                acc[g] = __builtin_amdgcn_mfma_f32_16x16x32_bf16(ha[kc], u, acc[g], 0, 0, 0);
            }
        }
        #pragma unroll
        for (int g = 0; g < 4; g++) uh1[g] = acc[g][0];  // all rows identical
    }

    // gates + store; mode 0: hbuf[parity], 1: xs[0] (h_m), 2: emb (coherent fp32 out)
    auto gates = [&](f32x4* acc, const float* bz, float* cc, int mode, int parity, int l) {
        #pragma unroll
        for (int r2 = 0; r2 < 4; r2++) {
            int m = q * 4 + r2;
            float zi = acc[0][r2] + bz[0];
            float zf = acc[1][r2] + bz[1];
            float zg = acc[2][r2] + bz[2];
            float zo = acc[3][r2] + bz[3];
            float c  = sigm(zf) * cc[r2] + sigm(zi) * tanh_f(zg);
            cc[r2] = c;
            float h  = sigm(zo) * tanh_f(c);
            if (mode == 0)      hbuf[parity][m][d] = f2bf(h);
            else if (mode == 1) xs[0][m][d] = f2bf(h);
            else cstore_f(emb + ((size_t)l * M_NODES + g0 + m) * DIM + d, h);
        }
    };

    // ---- gather-lane geometry (layer-invariant) + layer-1 index prefetch ----
    const bool isg = (tid < 384);
    int quarter = 0, slot = 0, node = 0, nidx = 0;
    if (isg) {
        quarter = tid & 3;
        int r = tid >> 2;
        slot = r >> 4;
        node = r & 15;
        if (slot < 4) nidx = prop_ids [((size_t)1 * M_NODES + g0 + node) * 4 + slot];
        else          nidx = super_ids[((size_t)1 * M_NODES + g0 + node) * 2 + (slot - 4)];
    }

    #pragma unroll 1
    for (int l = 1; l < LAYERS; l++) {
        const int gidx = nidx;
        // release: drain this block's layer-(l-1) emb stores to L3, then publish progress
        asm volatile("s_waitcnt vmcnt(0)" ::: "memory");
        __syncthreads();                        // also protects xs/hbuf reuse across layers
        if (tid == 0)
            __hip_atomic_store(&flags[(size_t)b * FLAGP], (unsigned)l,
                               __ATOMIC_RELAXED, __HIP_MEMORY_SCOPE_AGENT);

        // ---- gather: flag-gated row read (safe for rows of ANY layer) ----
        f32x4 vv[8];
        if (isg) {
            const int gl = gidx >> 11;                  // row's layer
            const int wb = (gidx >> 4) & (NBLK - 1);    // row's writer block
            if (gl > 0 && wb != b) {
                const unsigned* fp = flags + (size_t)wb * FLAGP;
                unsigned fv = __hip_atomic_load(fp, __ATOMIC_RELAXED, __HIP_MEMORY_SCOPE_AGENT);
                while ((int)fv <= gl) {                 // need flags[wb] >= gl+1
                    __builtin_amdgcn_s_sleep(8);
                    fv = __hip_atomic_load(fp, __ATOMIC_RELAXED, __HIP_MEMORY_SCOPE_AGENT);
                }
            }
            asm volatile("" ::: "memory");              // no load hoisting above the gate
            const f32x4* src = (const f32x4*)(emb + (size_t)gidx * DIM) + quarter * 8;
            #pragma unroll
            for (int j = 0; j < 8; j++) vv[j] = src[j];
            // fp32 -> bf16 LDS tile (8B vector writes)
            u16* dst = &xs[slot][node][0];
            int e0 = quarter * 32;
            #pragma unroll
            for (int j = 0; j < 8; j++) {
                f32x4 v = vv[j];
                ushort4 w;
                w.x = f2bf(v[0]); w.y = f2bf(v[1]); w.z = f2bf(v[2]); w.w = f2bf(v[3]);
                *(ushort4*)(dst + e0 + j * 4) = w;
            }
        }
        __syncthreads();

        // ---- next-layer index prefetch (pure input; hides under compute) ----
        if (isg && (l + 1) < LAYERS) {
            if (slot < 4) nidx = prop_ids [((size_t)(l + 1) * M_NODES + g0 + node) * 4 + slot];
            else          nidx = super_ids[((size_t)(l + 1) * M_NODES + g0 + node) * 2 + (slot - 4)];
        }

        // ---- Zx precompute: x@W for prop0..3 (wfm dies after this) ----
        f32x4 zxm[4][4];
        {
            s16x8 wfm[4][4];
            #pragma unroll
            for (int kc = 0; kc < 4; kc++)
                #pragma unroll
                for (int g = 0; g < 4; g++) wfm[kc][g] = ldB(0, kc, g);
            #pragma unroll
            for (int s = 0; s < 4; s++) {
                #pragma unroll
                for (int g = 0; g < 4; g++) zxm[s][g] = (f32x4){0.f, 0.f, 0.f, 0.f};
                #pragma unroll
                for (int kc = 0; kc < 4; kc++) {
                    s16x8 a = load_afrag(&xs[s][0][0], kc);
                    #pragma unroll
                    for (int g = 0; g < 4; g++)
                        zxm[s][g] = __builtin_amdgcn_mfma_f32_16x16x32_bf16(a, wfm[kc][g], zxm[s][g], 0, 0, 0);
                }
            }
        }

        // ---- recurrent LSTM_m: t=1..4 (t=0 hoisted) ----
        {
            s16x8 ufm[4][4];
            #pragma unroll
            for (int kc = 0; kc < 4; kc++)
                #pragma unroll
                for (int g = 0; g < 4; g++) ufm[kc][g] = ldB(1, kc, g);
            float cc[4] = {c1, c1, c1, c1};
            {   // t=1: z = x1@W + h1@U + b, all in registers
                f32x4 acc[4];
                #pragma unroll
                for (int g = 0; g < 4; g++) acc[g] = zxm[0][g] + uh1[g];
                gates(acc, bzm, cc, 0, 1, l);          // write hbuf[1]
            }
            #pragma unroll
            for (int t = 2; t <= 4; t++) {
                __syncthreads();
                const u16* hb = &hbuf[(t - 1) & 1][0][0];
                f32x4 acc[4];
                #pragma unroll
                for (int g = 0; g < 4; g++) acc[g] = zxm[t - 1][g];
                #pragma unroll
                for (int kc = 0; kc < 4; kc++) {
                    s16x8 a = load_afrag(hb, kc);
                    #pragma unroll
                    for (int g = 0; g < 4; g++)
                        acc[g] = __builtin_amdgcn_mfma_f32_16x16x32_bf16(a, ufm[kc][g], acc[g], 0, 0, 0);
                }
                if (t < 4) gates(acc, bzm, cc, 0, t & 1, l);
                else       gates(acc, bzm, cc, 1, 0, l);   // h_m -> xs[0]
            }
        }

        // ---- recurrent LSTM_s: seq = [sup0, sup1, h_m] ----
        {
            s16x8 ufs[4][4], wfs[4][4];
            #pragma unroll
            for (int kc = 0; kc < 4; kc++)
                #pragma unroll
                for (int g = 0; g < 4; g++) {
                    ufs[kc][g] = ldB(3, kc, g);
                    wfs[kc][g] = ldB(2, kc, g);
                }
            f32x4 acc0[4], zxs1[4];
            #pragma unroll
            for (int g = 0; g < 4; g++) { acc0[g] = (f32x4){0.f,0.f,0.f,0.f}; zxs1[g] = (f32x4){0.f,0.f,0.f,0.f}; }
            #pragma unroll
            for (int kc = 0; kc < 4; kc++) {
                s16x8 a4 = load_afrag(&xs[4][0][0], kc);
                s16x8 a5 = load_afrag(&xs[5][0][0], kc);
                #pragma unroll
                for (int g = 0; g < 4; g++) {
                    acc0[g] = __builtin_amdgcn_mfma_f32_16x16x32_bf16(a4, wfs[kc][g], acc0[g], 0, 0, 0);
                    zxs1[g] = __builtin_amdgcn_mfma_f32_16x16x32_bf16(a5, wfs[kc][g], zxs1[g], 0, 0, 0);
                }
            }
            float cc[4] = {0.f, 0.f, 0.f, 0.f};
            gates(acc0, bzs, cc, 0, 0, l);             // t=0: h=0, write hbuf[0]
            {   // t=1: x=sup1
                __syncthreads();
                const u16* hb = &hbuf[0][0][0];
                f32x4 acc[4];
                #pragma unroll
                for (int g = 0; g < 4; g++) acc[g] = zxs1[g];
                #pragma unroll
                for (int kc = 0; kc < 4; kc++) {
                    s16x8 a = load_afrag(hb, kc);
                    #pragma unroll
                    for (int g = 0; g < 4; g++)
                        acc[g] = __builtin_amdgcn_mfma_f32_16x16x32_bf16(a, ufs[kc][g], acc[g], 0, 0, 0);
                }
                gates(acc, bzs, cc, 0, 1, l);          // write hbuf[1]
            }
            {   // t=2: x=h_m (xs[0])
                __syncthreads();
                const u16* hb = &hbuf[1][0][0];
                f32x4 acc[4];
                #pragma unroll
                for (int g = 0; g < 4; g++) acc[g] = (f32x4){0.f, 0.f, 0.f, 0.f};
                #pragma unroll
                for (int kc = 0; kc < 4; kc++) {
                    s16x8 a  = load_afrag(&xs[0][0][0], kc);
                    s16x8 ah = load_afrag(hb, kc);
                    #pragma unroll
                    for (int g = 0; g < 4; g++) {
                        acc[g] = __builtin_amdgcn_mfma_f32_16x16x32_bf16(a,  wfs[kc][g], acc[g], 0, 0, 0);
                        acc[g] = __builtin_amdgcn_mfma_f32_16x16x32_bf16(ah, ufs[kc][g], acc[g], 0, 0, 0);
                    }
                }
                gates(acc, bzs, cc, 2, 0, l);          // coherent fp32 layer output
            }
        }
    }
}

// ----------------------------- fallback: proven per-layer kernel -----------------------------
template <bool PACKED>
__global__ __launch_bounds__(TPB, 1) void layer_kernel(
    float* __restrict__ emb, const int* __restrict__ prop_ids, const int* __restrict__ super_ids,
    const float* __restrict__ Wm, const float* __restrict__ Um, const float* __restrict__ bm,
    const float* __restrict__ Ws, const float* __restrict__ Us, const float* __restrict__ bs,
    const float* __restrict__ empty, const u16* __restrict__ packed, int l) {

    __shared__ __align__(16) u16  xs[6][CHUNK][XPAD];
    __shared__ __align__(16) u16  hbuf[2][CHUNK][XPAD];
    __shared__ __align__(16) u16  empty_s[XPAD];

    const int tid  = threadIdx.x;
    const int b    = blockIdx.x;
    const int g0   = b * CHUNK;
    const size_t row0 = (size_t)l * M_NODES + g0;

    const int wv   = tid >> 6;
    const int lane = tid & 63;
    const int q    = lane >> 4, nl = lane & 15;
    const int d    = wv * 16 + nl;

    if (tid < 384) {
        int quarter = tid & 3;
        int r    = tid >> 2;
        int slot = r >> 4;
        int node = r & 15;
        size_t idx;
        if (slot < 4) idx = (size_t)prop_ids [((size_t)l * M_NODES + g0 + node) * 4 + slot];
        else          idx = (size_t)super_ids[((size_t)l * M_NODES + g0 + node) * 2 + (slot - 4)];
        const float4* src = (const float4*)(emb + idx * DIM);
        u16* dst = &xs[slot][node][0];
        int e0 = quarter * 32;
        #pragma unroll
        for (int j = 0; j < 8; j++) {
            float4 v = src[(e0 >> 2) + j];
            int o = e0 + j * 4;
            dst[o] = f2bf(v.x); dst[o + 1] = f2bf(v.y);
            dst[o + 2] = f2bf(v.z); dst[o + 3] = f2bf(v.w);
        }
    } else if (tid < 384 + 128) {
        int dd = tid - 384;
        empty_s[dd] = f2bf(empty[dd]);
    }
    __syncthreads();

    auto load_bfrag_packed = [&](int mat, int kc, int g) -> s16x8 {
        return *(const s16x8*)(packed + ((((size_t)mat * 4 + kc) * 32 + (g * 8 + wv)) * 64 + lane) * 8);
    };
    auto load_bfrag_direct = [&](const float* B, int kc, int g) -> s16x8 {
        int kb = kc * 32 + q * 8;
        int n  = g * 128 + d;
        s16x8 f;
        #pragma unroll
        for (int j = 0; j < 8; j++) f[j] = (short)f2bf(B[(size_t)(kb + j) * FD + n]);
        return f;
    };
    auto load_afrag = [&](const u16* X, int kc) -> s16x8 {
        return *(const s16x8*)(X + (size_t)nl * XPAD + kc * 32 + q * 8);
    };

    auto run_phase = [&](const float* Wg, const float* Ug, const float* bias,
                         int matW, int matU, int nsteps, const int* slots,
                         bool write_hm, bool write_out) {
        s16x8 wf[4][4], uf[4][4];
        #pragma unroll
        for (int kc = 0; kc < 4; kc++) {
            #pragma unroll
            for (int g = 0; g < 4; g++) {
                if (PACKED) { wf[kc][g] = load_bfrag_packed(matW, kc, g);
                              uf[kc][g] = load_bfrag_packed(matU, kc, g); }
                else        { wf[kc][g] = load_bfrag_direct(Wg, kc, g);
                              uf[kc][g] = load_bfrag_direct(Ug, kc, g); }
            }
        }
        float bz[4];
        #pragma unroll
        for (int g = 0; g < 4; g++) bz[g] = bias[g * 128 + d];
        float cc[4] = {0.f, 0.f, 0.f, 0.f};

        #pragma unroll 1
        for (int t = 0; t < nsteps; t++) {
            int s = slots[t];
            f32x4 acc[4];
            #pragma unroll
            for (int g = 0; g < 4; g++) acc[g] = (f32x4){0.f, 0.f, 0.f, 0.f};
            #pragma unroll
            for (int kc = 0; kc < 4; kc++) {
                s16x8 a = (s < 0) ? *(const s16x8*)(&empty_s[kc * 32 + q * 8])
                                  : load_afrag(&xs[s][0][0], kc);
                #pragma unroll
                for (int g = 0; g < 4; g++)
                    acc[g] = __builtin_amdgcn_mfma_f32_16x16x32_bf16(a, wf[kc][g], acc[g], 0, 0, 0);
            }
            if (t > 0) {
                __syncthreads();
                const u16* hb = &hbuf[(t - 1) & 1][0][0];
                #pragma unroll
                for (int kc = 0; kc < 4; kc++) {
                    s16x8 a = load_afrag(hb, kc);
                    #pragma unroll
                    for (int g = 0; g < 4; g++)
                        acc[g] = __builtin_amdgcn_mfma_f32_16x16x32_bf16(a, uf[kc][g], acc[g], 0, 0, 0);
                }
            }
            bool last = (t == nsteps - 1);
            #pragma unroll
            for (int r2 = 0; r2 < 4; r2++) {
                int m = q * 4 + r2;
                float zi = acc[0][r2] + bz[0];
                float zf = acc[1][r2] + bz[1];
                float zg = acc[2][r2] + bz[2];
                float zo = acc[3][r2] + bz[3];
                float c  = sigm(zf) * cc[r2] + sigm(zi) * tanh_f(zg);
                cc[r2] = c;
                float h  = sigm(zo) * tanh_f(c);
                if (!last)          hbuf[t & 1][m][d] = f2bf(h);
                else if (write_hm)  xs[0][m][d] = f2bf(h);
                else if (write_out) emb[(row0 + m) * DIM + d] = h;
            }
        }
    };

    {
        const int slots_m[5] = {-1, 0, 1, 2, 3};
        run_phase(Wm, Um, bm, 0, 1, 5, slots_m, true, false);
    }
    {
        const int slots_s[3] = {4, 5, 0};
        run_phase(Ws, Us, bs, 2, 3, 3, slots_s, false, true);
    }
}

extern "C" void kernel_launch(void* const* d_in, const int* in_sizes, int n_in,
                              void* d_out, int out_size, void* d_ws, size_t ws_size,
                              hipStream_t stream) {
    const int*   names = (const int*)d_in[0];
    const int*   pids  = (const int*)d_in[1];
    const int*   sids  = (const int*)d_in[2];
    const float* table = (const float*)d_in[3];
    const float* Wm    = (const float*)d_in[4];
    const float* Um    = (const float*)d_in[5];
    const float* bm    = (const float*)d_in[6];
    const float* Ws    = (const float*)d_in[7];
    const float* Us    = (const float*)d_in[8];
    const float* bs    = (const float*)d_in[9];
    const float* empt  = (const float*)d_in[10];
    float* emb  = (float*)d_out;
    u16* packed = (u16*)d_ws;

    l0_kernel<<<256, 256, 0, stream>>>(names, table, emb);

    const size_t packed_bytes = (size_t)4 * 4 * 32 * 64 * 8 * sizeof(u16);  // 512 KB
    const bool ws_ok = ws_size >= packed_bytes + NBLK * FLAGP * sizeof(unsigned);

    if (ws_ok) {
        unsigned* flags = (unsigned*)((char*)d_ws + packed_bytes);
        repack_kernel<<<128, 256, 0, stream>>>(Wm, Um, Ws, Us, packed, flags);

        void* args[] = {(void*)&emb, (void*)&pids, (void*)&sids, (void*)&Wm, (void*)&Um, (void*)&bm,
                        (void*)&Ws, (void*)&Us, (void*)&bs, (void*)&empt, (void*)&packed, (void*)&flags};
        void (*kptr)(float*, const int*, const int*, const float*, const float*, const float*,
                     const float*, const float*, const float*, const float*, const u16*, unsigned*) =
            fused_kernel;
        hipError_t err = hipLaunchCooperativeKernel((const void*)kptr, dim3(NBLK), dim3(TPB),
                                                    args, 0, stream);
        if (err == hipSuccess) return;
        // coop launch failed -> proven per-layer path (packed)
        for (int l = 1; l < LAYERS; l++)
            layer_kernel<true><<<NBLK, TPB, 0, stream>>>(emb, pids, sids, Wm, Um, bm,
                                                         Ws, Us, bs, empt, packed, l);
    } else {
        for (int l = 1; l < LAYERS; l++)
            layer_kernel<false><<<NBLK, TPB, 0, stream>>>(emb, pids, sids, Wm, Um, bm,
                                                          Ws, Us, bs, empt, packed, l);
    }
}